// Round 1
// baseline (532.559 us; speedup 1.0000x reference)
//
#include <hip/hip_runtime.h>
#include <math.h>

#define B_ 64
#define NV_ 256
#define N_ 768
#define MAXNNZ 16

#define BM 64
#define BN 64
#define BK 16

// ---------------- build normalized sparse adjacency ----------------

__global__ __launch_bounds__(256) void k_build_deg(const float* __restrict__ A,
                                                   float* __restrict__ dinv) {
    int i = blockIdx.x;
    float s = 0.f;
    for (int j = threadIdx.x; j < N_; j += 256) s += A[i * N_ + j];
    __shared__ float red[256];
    red[threadIdx.x] = s;
    __syncthreads();
    for (int off = 128; off > 0; off >>= 1) {
        if (threadIdx.x < off) red[threadIdx.x] += red[threadIdx.x + off];
        __syncthreads();
    }
    if (threadIdx.x == 0) {
        float deg = red[0];
        dinv[i] = (deg == 0.f) ? 0.f : 1.0f / sqrtf(deg);
    }
}

__global__ __launch_bounds__(256) void k_build_sparse(const float* __restrict__ A,
                                                      const float* __restrict__ dinv,
                                                      int* __restrict__ cols,
                                                      float* __restrict__ vals,
                                                      int* __restrict__ nnzArr) {
    int i = blockIdx.x * blockDim.x + threadIdx.x;
    if (i >= N_) return;
    float di = dinv[i];
    int cnt = 0;
    for (int j = 0; j < N_; ++j) {
        float a = A[i * N_ + j];
        if (a != 0.f && cnt < MAXNNZ) {
            cols[i * MAXNNZ + cnt] = j;
            vals[i * MAXNNZ + cnt] = a * di * dinv[j];
            ++cnt;
        }
    }
    nnzArr[i] = cnt;
}

// ---------------- small utility kernels ----------------

__global__ __launch_bounds__(256) void k_copy(const float* __restrict__ src,
                                              float* __restrict__ dst, int total) {
    for (int e = blockIdx.x * blockDim.x + threadIdx.x; e < total;
         e += gridDim.x * blockDim.x)
        dst[e] = src[e];
}

// overwrite clamped nodes' first-3 features with `inputs` values
__global__ __launch_bounds__(256) void k_clamp_small(float* __restrict__ T, int stride,
                                                     const float* __restrict__ inputs,
                                                     const int* __restrict__ psel, int np,
                                                     const int* __restrict__ c1, int n1,
                                                     const int* __restrict__ c2, int n2) {
    int tot = np + n1 + n2;
    int e = blockIdx.x * blockDim.x + threadIdx.x;
    if (e >= B_ * tot * 3) return;
    int f = e % 3;
    int s = (e / 3) % tot;
    int b = e / (3 * tot);
    int node;
    if (s < np) node = psel[s];
    else if (s < np + n1) node = NV_ + c1[s - np];
    else node = 2 * NV_ + c2[s - np - n1];
    T[((size_t)b * N_ + node) * stride + f] = inputs[((size_t)b * N_ + node) * 3 + f];
}

// ---------------- fp32 GEMM: C[M,Nout] = H[M,K] @ W[Nout,K]^T + bias ----------------

__global__ __launch_bounds__(256) void k_gemm_bias(const float* __restrict__ H,
                                                   const float* __restrict__ W,
                                                   const float* __restrict__ bias,
                                                   float* __restrict__ C,
                                                   int M, int K, int Nout) {
    __shared__ float Hs[BM][BK + 1];
    __shared__ float Ws[BK][BN + 1];

    int row0 = blockIdx.y * BM;
    int col0 = blockIdx.x * BN;
    int tid = threadIdx.x;
    int tx = tid & 15;        // 0..15 -> output col group
    int ty = tid >> 4;        // 0..15 -> output row group

    float acc[4][4];
#pragma unroll
    for (int i = 0; i < 4; ++i)
#pragma unroll
        for (int j = 0; j < 4; ++j) acc[i][j] = 0.f;

    for (int k0 = 0; k0 < K; k0 += BK) {
        int l0 = tid * 4;
#pragma unroll
        for (int q = 0; q < 4; ++q) {
            int l = l0 + q;
            int m = l >> 4, k = l & 15;
            Hs[m][k] = (k0 + k < K) ? H[(size_t)(row0 + m) * K + k0 + k] : 0.f;
        }
#pragma unroll
        for (int q = 0; q < 4; ++q) {
            int l = l0 + q;
            int n = l >> 4, k = l & 15;
            int col = col0 + n;
            Ws[k][n] = (col < Nout && k0 + k < K) ? W[(size_t)col * K + k0 + k] : 0.f;
        }
        __syncthreads();

#pragma unroll
        for (int kk = 0; kk < BK; ++kk) {
            float a[4], bb[4];
#pragma unroll
            for (int i = 0; i < 4; ++i) a[i] = Hs[ty * 4 + i][kk];
#pragma unroll
            for (int j = 0; j < 4; ++j) bb[j] = Ws[kk][tx * 4 + j];
#pragma unroll
            for (int i = 0; i < 4; ++i)
#pragma unroll
                for (int j = 0; j < 4; ++j) acc[i][j] += a[i] * bb[j];
        }
        __syncthreads();
    }

#pragma unroll
    for (int i = 0; i < 4; ++i) {
        int r = row0 + ty * 4 + i;
        if (r >= M) continue;
#pragma unroll
        for (int j = 0; j < 4; ++j) {
            int c = col0 + tx * 4 + j;
            if (c < Nout) C[(size_t)r * Nout + c] = acc[i][j] + bias[c];
        }
    }
}

// ---------------- sparse aggregation: Out[b,i,f] = sum_k val * Z[b,col,f] ----------------

__global__ __launch_bounds__(256) void k_agg(const float* __restrict__ Z,
                                             const int* __restrict__ cols,
                                             const float* __restrict__ vals,
                                             const int* __restrict__ nnzArr,
                                             float* __restrict__ Out,
                                             int F, int total, int do_relu) {
    for (int e = blockIdx.x * blockDim.x + threadIdx.x; e < total;
         e += gridDim.x * blockDim.x) {
        int f = e % F;
        int bi = e / F;
        int i = bi % N_;
        int base = bi - i;  // b*N_
        int n = nnzArr[i];
        float s = 0.f;
        for (int k = 0; k < n; ++k) {
            s += vals[i * MAXNNZ + k] * Z[(size_t)(base + cols[i * MAXNNZ + k]) * F + f];
        }
        if (do_relu) s = fmaxf(s, 0.f);
        Out[e] = s;
    }
}

// ---------------- launch ----------------

extern "C" void kernel_launch(void* const* d_in, const int* in_sizes, int n_in,
                              void* d_out, int out_size, void* d_ws, size_t ws_size,
                              hipStream_t stream) {
    const float* x      = (const float*)d_in[0];
    const float* inputs = (const float*)d_in[1];
    const float* A      = (const float*)d_in[2];
    const float* W1     = (const float*)d_in[3];
    const float* b1     = (const float*)d_in[4];
    const float* W2     = (const float*)d_in[5];
    const float* b2     = (const float*)d_in[6];
    const float* W3     = (const float*)d_in[7];
    const float* b3     = (const float*)d_in[8];
    const float* W4     = (const float*)d_in[9];
    const float* b4     = (const float*)d_in[10];
    const int* psel     = (const int*)d_in[11];
    const int* c1sel    = (const int*)d_in[12];
    const int* c2sel    = (const int*)d_in[13];
    int np = in_sizes[11], n1 = in_sizes[12], n2 = in_sizes[13];
    float* out = (float*)d_out;

    char* ws = (char*)d_ws;
    float* dinv = (float*)(ws + 0);                  //   768 f
    int*   nnzA = (int*)(ws + 3072);                 //   768 i
    int*   cols = (int*)(ws + 6144);                 //  768*16 i
    float* vals = (float*)(ws + 6144 + 49152);       //  768*16 f
    float* X0   = (float*)(ws + 104448);             //  B*N*6 f
    float* bufA = (float*)(ws + 1284096);            //  B*N*256 f (50.3MB)
    float* bufB = (float*)(ws + 1284096 + 50331648); //  B*N*256 f (50.3MB)

    const int M = B_ * N_;  // 49152

    // sparse A_norm
    k_build_deg<<<N_, 256, 0, stream>>>(A, dinv);
    k_build_sparse<<<(N_ + 255) / 256, 256, 0, stream>>>(A, dinv, cols, vals, nnzA);

    // clamped input features
    k_copy<<<(M * 6 + 255) / 256, 256, 0, stream>>>(x, X0, M * 6);
    {
        int tot = B_ * (np + n1 + n2) * 3;
        k_clamp_small<<<(tot + 255) / 256, 256, 0, stream>>>(X0, 6, inputs, psel, np,
                                                             c1sel, n1, c2sel, n2);
    }

    auto agg_grid = [](int total) {
        int g = (total + 255) / 256;
        return g > 8192 ? 8192 : g;
    };

    // layer 1: (M,6) -> (M,256), relu
    {
        dim3 g((256 + BN - 1) / BN, M / BM);
        k_gemm_bias<<<g, 256, 0, stream>>>(X0, W1, b1, bufA, M, 6, 256);
        int total = M * 256;
        k_agg<<<agg_grid(total), 256, 0, stream>>>(bufA, cols, vals, nnzA, bufB, 256,
                                                   total, 1);
    }
    // layer 2: (M,256) -> (M,128), relu
    {
        dim3 g((128 + BN - 1) / BN, M / BM);
        k_gemm_bias<<<g, 256, 0, stream>>>(bufB, W2, b2, bufA, M, 256, 128);
        int total = M * 128;
        k_agg<<<agg_grid(total), 256, 0, stream>>>(bufA, cols, vals, nnzA, bufB, 128,
                                                   total, 1);
    }
    // layer 3: (M,128) -> (M,128), no relu
    {
        dim3 g((128 + BN - 1) / BN, M / BM);
        k_gemm_bias<<<g, 256, 0, stream>>>(bufB, W3, b3, bufA, M, 128, 128);
        int total = M * 128;
        k_agg<<<agg_grid(total), 256, 0, stream>>>(bufA, cols, vals, nnzA, bufB, 128,
                                                   total, 0);
    }
    // layer 4: (M,128) -> (M,3), no relu, straight to out
    {
        dim3 g((3 + BN - 1) / BN, M / BM);
        k_gemm_bias<<<g, 256, 0, stream>>>(bufB, W4, b4, bufA, M, 128, 3);
        int total = M * 3;
        k_agg<<<agg_grid(total), 256, 0, stream>>>(bufA, cols, vals, nnzA, out, 3,
                                                   total, 0);
    }
    // clamp outputs
    {
        int tot = B_ * (np + n1 + n2) * 3;
        k_clamp_small<<<(tot + 255) / 256, 256, 0, stream>>>(out, 3, inputs, psel, np,
                                                             c1sel, n1, c2sel, n2);
    }
}

// Round 3
// 238.438 us; speedup vs baseline: 2.2335x; 2.2335x over previous
//
#include <hip/hip_runtime.h>
#include <math.h>

#define B_ 64
#define NV_ 256
#define N_ 768
#define MAXNNZ 16
#define M_ (B_ * N_)   // 49152 rows

typedef unsigned short us8 __attribute__((ext_vector_type(8)));
typedef __bf16 bf16x8 __attribute__((ext_vector_type(8)));
typedef float f32x4 __attribute__((ext_vector_type(4)));

__device__ inline float bf2f(unsigned short u) {
    return __uint_as_float(((unsigned int)u) << 16);
}
__device__ inline unsigned short f2bf(float f) {
    unsigned int u = __float_as_uint(f);
    unsigned int r = u + 0x7fffu + ((u >> 16) & 1u);
    return (unsigned short)(r >> 16);
}
__device__ inline bf16x8 ld_bf8(const unsigned short* p) {
    us8 u = *(const us8*)p;
    return __builtin_bit_cast(bf16x8, u);
}

// ---------------- build normalized sparse adjacency ----------------

__global__ __launch_bounds__(256) void k_build_deg(const float* __restrict__ A,
                                                   float* __restrict__ dinv) {
    int i = blockIdx.x;
    float s = 0.f;
    for (int j = threadIdx.x; j < N_; j += 256) s += A[i * N_ + j];
    __shared__ float red[256];
    red[threadIdx.x] = s;
    __syncthreads();
    for (int off = 128; off > 0; off >>= 1) {
        if (threadIdx.x < off) red[threadIdx.x] += red[threadIdx.x + off];
        __syncthreads();
    }
    if (threadIdx.x == 0) {
        float deg = red[0];
        dinv[i] = (deg == 0.f) ? 0.f : 1.0f / sqrtf(deg);
    }
}

__global__ __launch_bounds__(256) void k_build_sparse(const float* __restrict__ A,
                                                      const float* __restrict__ dinv,
                                                      int* __restrict__ cols,
                                                      float* __restrict__ vals,
                                                      int* __restrict__ nnzArr,
                                                      float* __restrict__ rowsum) {
    int i = blockIdx.x * blockDim.x + threadIdx.x;
    if (i >= N_) return;
    float di = dinv[i];
    int cnt = 0;
    float rs = 0.f;
    for (int j = 0; j < N_; ++j) {
        float a = A[i * N_ + j];
        if (a != 0.f && cnt < MAXNNZ) {
            float v = a * di * dinv[j];
            cols[i * MAXNNZ + cnt] = j;
            vals[i * MAXNNZ + cnt] = v;
            rs += v;
            ++cnt;
        }
    }
    nnzArr[i] = cnt;
    rowsum[i] = rs;
}

__global__ void k_clampflag(int* __restrict__ flag, const int* __restrict__ p, int np,
                            const int* __restrict__ c1, int n1,
                            const int* __restrict__ c2, int n2) {
    int t = threadIdx.x;
    if (t < N_) flag[t] = 0;
    __syncthreads();
    if (t < np) flag[p[t]] = 1;
    else if (t - np < n1) flag[NV_ + c1[t - np]] = 1;
    else if (t - np - n1 < n2) flag[2 * NV_ + c2[t - np - n1]] = 1;
}

__global__ __launch_bounds__(256) void k_convW(const float* __restrict__ W2,
                                               const float* __restrict__ W3,
                                               unsigned short* __restrict__ W2b,
                                               unsigned short* __restrict__ W3b) {
    int idx = blockIdx.x * 256 + threadIdx.x;
    if (idx < 128 * 256) W2b[idx] = f2bf(W2[idx]);
    else {
        int j = idx - 128 * 256;
        if (j < 128 * 128) W3b[j] = f2bf(W3[j]);
    }
}

// ---- layer-1 input aggregation at F=6 (with clamp folded in), fp32 out ----

__global__ __launch_bounds__(256) void k_agg1(const float* __restrict__ x,
                                              const float* __restrict__ inputs,
                                              const int* __restrict__ cols,
                                              const float* __restrict__ vals,
                                              const int* __restrict__ nnzArr,
                                              const int* __restrict__ clampf,
                                              float* __restrict__ Xagg) {
    int idx = blockIdx.x * 256 + threadIdx.x;
    if (idx >= M_ * 6) return;
    int f = idx % 6;
    int r = idx / 6;
    int i = r % N_;
    int base = r - i;
    int n = nnzArr[i];
    float s = 0.f;
    for (int k = 0; k < n; ++k) {
        int c = cols[i * MAXNNZ + k];
        float val;
        if (f < 3 && clampf[c]) val = inputs[(size_t)(base + c) * 3 + f];
        else val = x[(size_t)(base + c) * 6 + f];
        s += vals[i * MAXNNZ + k] * val;
    }
    Xagg[idx] = s;
}

// ---- layer 1 linear: H1 = relu(Xagg @ W1^T + rowsum*b1), bf16 out ----

__global__ __launch_bounds__(256) void k_gemm1(const float* __restrict__ Xagg,
                                               const float* __restrict__ W1,
                                               const float* __restrict__ b1,
                                               const float* __restrict__ rowsum,
                                               unsigned short* __restrict__ H1) {
    __shared__ float W1s[256 * 6];
    __shared__ float b1s[256];
    int tid = threadIdx.x;
    for (int t = tid; t < 256 * 6; t += 256) W1s[t] = W1[t];
    b1s[tid] = b1[tid];
    __syncthreads();

    int idx = blockIdx.x * 256 + tid;
    int r = idx >> 5;
    int cg = idx & 31;
    int i = r % N_;
    float xa[6];
#pragma unroll
    for (int k = 0; k < 6; ++k) xa[k] = Xagg[(size_t)r * 6 + k];
    float rs = rowsum[i];
    us8 o;
#pragma unroll
    for (int c8 = 0; c8 < 8; ++c8) {
        int c = cg * 8 + c8;
        float s = rs * b1s[c];
#pragma unroll
        for (int k = 0; k < 6; ++k) s += xa[k] * W1s[c * 6 + k];
        o[c8] = f2bf(fmaxf(s, 0.f));
    }
    *(us8*)(H1 + (size_t)r * 256 + cg * 8) = o;
}

// ---- MFMA GEMM: C[M,128] = H[M,K](bf16) @ W[128,K](bf16)^T + bias, bf16 out ----
// block = 4 waves, each wave computes 16 rows x 128 cols; no LDS, no barriers.

template <int K>
__global__ __launch_bounds__(256) void k_gemm_mfma(const unsigned short* __restrict__ H,
                                                   const unsigned short* __restrict__ Wb,
                                                   const float* __restrict__ bias,
                                                   unsigned short* __restrict__ C) {
    int tid = threadIdx.x;
    int lane = tid & 63;
    int wave = tid >> 6;
    int r0 = blockIdx.x * 64 + wave * 16;
    int lrow = lane & 15;
    int kgrp = lane >> 4;  // 0..3

    const unsigned short* Arow = H + (size_t)(r0 + lrow) * K + kgrp * 8;

    f32x4 acc[8];
#pragma unroll
    for (int j = 0; j < 8; ++j) acc[j] = (f32x4){0.f, 0.f, 0.f, 0.f};

    constexpr int NS = K / 32;
    bf16x8 a_cur = ld_bf8(Arow);
#pragma unroll
    for (int s = 0; s < NS; ++s) {
        bf16x8 a_next = a_cur;
        if (s + 1 < NS) a_next = ld_bf8(Arow + (s + 1) * 32);
#pragma unroll
        for (int j = 0; j < 8; ++j) {
            bf16x8 b = ld_bf8(Wb + (size_t)(j * 16 + lrow) * K + s * 32 + kgrp * 8);
            acc[j] = __builtin_amdgcn_mfma_f32_16x16x32_bf16(a_cur, b, acc[j], 0, 0, 0);
        }
        a_cur = a_next;
    }

#pragma unroll
    for (int j = 0; j < 8; ++j) {
        int n = j * 16 + lrow;      // D: col = lane&15
        float bv = bias[n];
#pragma unroll
        for (int e = 0; e < 4; ++e) {
            int row = r0 + kgrp * 4 + e;  // D: row = 4*(lane>>4)+e
            C[(size_t)row * 128 + n] = f2bf(acc[j][e] + bv);
        }
    }
}

// ---- sparse aggregation at F=128, bf16 in/out, optional relu ----

__global__ __launch_bounds__(256) void k_aggF(const unsigned short* __restrict__ Z,
                                              const int* __restrict__ cols,
                                              const float* __restrict__ vals,
                                              const int* __restrict__ nnzArr,
                                              unsigned short* __restrict__ Out,
                                              int relu) {
    int idx = blockIdx.x * 256 + threadIdx.x;
    int fg = idx & 15;
    int r = idx >> 4;
    int i = r % N_;
    int base = r - i;
    int n = nnzArr[i];
    float acc[8];
#pragma unroll
    for (int e = 0; e < 8; ++e) acc[e] = 0.f;
    for (int k = 0; k < n; ++k) {
        int c = cols[i * MAXNNZ + k];
        float v = vals[i * MAXNNZ + k];
        us8 z = *(const us8*)(Z + (size_t)(base + c) * 128 + fg * 8);
#pragma unroll
        for (int e = 0; e < 8; ++e) acc[e] += v * bf2f(z[e]);
    }
    us8 o;
#pragma unroll
    for (int e = 0; e < 8; ++e) {
        float s = acc[e];
        if (relu) s = fmaxf(s, 0.f);
        o[e] = f2bf(s);
    }
    *(us8*)(Out + (size_t)r * 128 + fg * 8) = o;
}

// ---- layer 4 linear: T4[M,3] = H3 @ W4^T + b4, fp32 out ----

__global__ __launch_bounds__(256) void k_gemm4(const unsigned short* __restrict__ H3,
                                               const float* __restrict__ W4,
                                               const float* __restrict__ b4,
                                               float* __restrict__ T4) {
    __shared__ float W4s[128 * 3];
    int tid = threadIdx.x;
    for (int t = tid; t < 384; t += 256) {   // FIX: block has 256 threads, 384 entries
        int c = t % 3, k = t / 3;
        W4s[t] = W4[c * 128 + k];
    }
    __syncthreads();

    int idx = blockIdx.x * 256 + tid;
    int r = idx >> 2;
    int q = idx & 3;
    float a0 = 0.f, a1 = 0.f, a2 = 0.f;
    const unsigned short* row = H3 + (size_t)r * 128;
#pragma unroll
    for (int t = 0; t < 4; ++t) {
        int k0 = t * 32 + q * 8;
        us8 z = *(const us8*)(row + k0);
#pragma unroll
        for (int e = 0; e < 8; ++e) {
            float f = bf2f(z[e]);
            int k = k0 + e;
            a0 += f * W4s[k * 3 + 0];
            a1 += f * W4s[k * 3 + 1];
            a2 += f * W4s[k * 3 + 2];
        }
    }
#pragma unroll
    for (int m = 1; m < 4; m <<= 1) {
        a0 += __shfl_xor(a0, m, 4);
        a1 += __shfl_xor(a1, m, 4);
        a2 += __shfl_xor(a2, m, 4);
    }
    if (q == 0) {
        T4[(size_t)r * 3 + 0] = a0 + b4[0];
        T4[(size_t)r * 3 + 1] = a1 + b4[1];
        T4[(size_t)r * 3 + 2] = a2 + b4[2];
    }
}

// ---- final aggregation at F=3 with output clamp, fp32 out ----

__global__ __launch_bounds__(256) void k_agg_out(const float* __restrict__ T4,
                                                 const float* __restrict__ inputs,
                                                 const int* __restrict__ cols,
                                                 const float* __restrict__ vals,
                                                 const int* __restrict__ nnzArr,
                                                 const int* __restrict__ clampf,
                                                 float* __restrict__ out) {
    int idx = blockIdx.x * 256 + threadIdx.x;
    if (idx >= M_ * 3) return;
    int f = idx % 3;
    int r = idx / 3;
    int i = r % N_;
    int base = r - i;
    if (clampf[i]) {
        out[idx] = inputs[(size_t)r * 3 + f];
        return;
    }
    int n = nnzArr[i];
    float s = 0.f;
    for (int k = 0; k < n; ++k) {
        int c = cols[i * MAXNNZ + k];
        s += vals[i * MAXNNZ + k] * T4[(size_t)(base + c) * 3 + f];
    }
    out[idx] = s;
}

// ---------------- launch ----------------

extern "C" void kernel_launch(void* const* d_in, const int* in_sizes, int n_in,
                              void* d_out, int out_size, void* d_ws, size_t ws_size,
                              hipStream_t stream) {
    const float* x      = (const float*)d_in[0];
    const float* inputs = (const float*)d_in[1];
    const float* A      = (const float*)d_in[2];
    const float* W1     = (const float*)d_in[3];
    const float* b1     = (const float*)d_in[4];
    const float* W2     = (const float*)d_in[5];
    const float* b2     = (const float*)d_in[6];
    const float* W3     = (const float*)d_in[7];
    const float* b3     = (const float*)d_in[8];
    const float* W4     = (const float*)d_in[9];
    const float* b4     = (const float*)d_in[10];
    const int* psel     = (const int*)d_in[11];
    const int* c1sel    = (const int*)d_in[12];
    const int* c2sel    = (const int*)d_in[13];
    int np = in_sizes[11], n1 = in_sizes[12], n2 = in_sizes[13];
    float* out = (float*)d_out;

    char* ws = (char*)d_ws;
    float* dinv            = (float*)(ws + 0);
    float* rowsum          = (float*)(ws + 3072);
    int*   nnzA            = (int*)(ws + 6144);
    int*   clampf          = (int*)(ws + 9216);
    int*   cols            = (int*)(ws + 12288);
    float* vals            = (float*)(ws + 61440);
    unsigned short* W2b    = (unsigned short*)(ws + 110592);
    unsigned short* W3b    = (unsigned short*)(ws + 176128);
    float* Xagg            = (float*)(ws + 208896);
    float* T4              = (float*)(ws + 1388544);
    unsigned short* H1     = (unsigned short*)(ws + 1978368);
    unsigned short* T2     = (unsigned short*)(ws + 27144192);
    unsigned short* H2     = (unsigned short*)(ws + 39727104);
    unsigned short* T3     = (unsigned short*)(ws + 52310016);
    unsigned short* H3     = (unsigned short*)(ws + 64892928);

    // graph build (tiny)
    k_build_deg<<<N_, 256, 0, stream>>>(A, dinv);
    k_build_sparse<<<3, 256, 0, stream>>>(A, dinv, cols, vals, nnzA, rowsum);
    k_clampflag<<<1, 768, 0, stream>>>(clampf, psel, np, c1sel, n1, c2sel, n2);
    k_convW<<<192, 256, 0, stream>>>(W2, W3, W2b, W3b);

    // layer 1: aggregate at F=6, then linear 6->256 with rowsum-scaled bias + relu
    k_agg1<<<(M_ * 6) / 256, 256, 0, stream>>>(x, inputs, cols, vals, nnzA, clampf, Xagg);
    k_gemm1<<<(M_ * 32) / 256, 256, 0, stream>>>(Xagg, W1, b1, rowsum, H1);

    // layer 2: MFMA GEMM 256->128, then aggregate + relu
    k_gemm_mfma<256><<<M_ / 64, 256, 0, stream>>>(H1, W2b, b2, T2);
    k_aggF<<<(M_ * 16) / 256, 256, 0, stream>>>(T2, cols, vals, nnzA, H2, 1);

    // layer 3: MFMA GEMM 128->128, then aggregate (no relu)
    k_gemm_mfma<128><<<M_ / 64, 256, 0, stream>>>(H2, W3b, b3, T3);
    k_aggF<<<(M_ * 16) / 256, 256, 0, stream>>>(T3, cols, vals, nnzA, H3, 0);

    // layer 4: linear 128->3, then aggregate at F=3 with output clamp
    k_gemm4<<<(M_ * 4) / 256, 256, 0, stream>>>(H3, W4, b4, T4);
    k_agg_out<<<(M_ * 3 + 255) / 256, 256, 0, stream>>>(T4, inputs, cols, vals, nnzA,
                                                        clampf, out);
}

// Round 4
// 113.563 us; speedup vs baseline: 4.6896x; 2.0996x over previous
//
#include <hip/hip_runtime.h>
#include <math.h>

#define B_ 64
#define NV_ 256
#define N_ 768
#define MAXNNZ 16
#define M_ (B_ * N_)   // 49152 rows

typedef unsigned short us8 __attribute__((ext_vector_type(8)));
typedef __bf16 bf16x8 __attribute__((ext_vector_type(8)));
typedef float f32x4 __attribute__((ext_vector_type(4)));

__device__ inline float bf2f(unsigned short u) {
    return __uint_as_float(((unsigned int)u) << 16);
}
__device__ inline unsigned short f2bf(float f) {
    unsigned int u = __float_as_uint(f);
    unsigned int r = u + 0x7fffu + ((u >> 16) & 1u);
    return (unsigned short)(r >> 16);
}
__device__ inline bf16x8 ld_bf8(const unsigned short* p) {
    us8 u = *(const us8*)p;
    return __builtin_bit_cast(bf16x8, u);
}

// ---------------- build normalized sparse adjacency ----------------

__global__ __launch_bounds__(256) void k_build_deg(const float* __restrict__ A,
                                                   float* __restrict__ dinv) {
    int i = blockIdx.x;
    float s = 0.f;
    for (int j = threadIdx.x; j < N_; j += 256) s += A[i * N_ + j];
    __shared__ float red[256];
    red[threadIdx.x] = s;
    __syncthreads();
    for (int off = 128; off > 0; off >>= 1) {
        if (threadIdx.x < off) red[threadIdx.x] += red[threadIdx.x + off];
        __syncthreads();
    }
    if (threadIdx.x == 0) {
        float deg = red[0];
        dinv[i] = (deg == 0.f) ? 0.f : 1.0f / sqrtf(deg);
    }
}

// one wave per row: ballot-compacted sparse extraction
__global__ __launch_bounds__(256) void k_build_sparse(const float* __restrict__ A,
                                                      const float* __restrict__ dinv,
                                                      int* __restrict__ cols,
                                                      float* __restrict__ vals,
                                                      int* __restrict__ nnzArr,
                                                      float* __restrict__ rowsum) {
    int wid = (blockIdx.x * 256 + threadIdx.x) >> 6;  // row
    int lane = threadIdx.x & 63;
    if (wid >= N_) return;
    int i = wid;
    float di = dinv[i];
    int cnt = 0;
    float rs = 0.f;
#pragma unroll
    for (int c0 = 0; c0 < N_; c0 += 64) {
        int c = c0 + lane;
        float a = A[(size_t)i * N_ + c];
        unsigned long long m = __ballot(a != 0.f);
        float v = 0.f;
        if (a != 0.f) {
            v = a * di * dinv[c];
            int pos = cnt + __popcll(m & ((1ull << lane) - 1ull));
            if (pos < MAXNNZ) {
                cols[i * MAXNNZ + pos] = c;
                vals[i * MAXNNZ + pos] = v;
            }
        }
        cnt += (int)__popcll(m);
        rs += v;
    }
#pragma unroll
    for (int o = 32; o > 0; o >>= 1) rs += __shfl_xor(rs, o);
    if (lane == 0) {
        nnzArr[i] = cnt;
        rowsum[i] = rs;
    }
}

__global__ void k_clampflag(int* __restrict__ flag, const int* __restrict__ p, int np,
                            const int* __restrict__ c1, int n1,
                            const int* __restrict__ c2, int n2) {
    int t = threadIdx.x;
    if (t < N_) flag[t] = 0;
    __syncthreads();
    if (t < np) flag[p[t]] = 1;
    else if (t - np < n1) flag[NV_ + c1[t - np]] = 1;
    else if (t - np - n1 < n2) flag[2 * NV_ + c2[t - np - n1]] = 1;
}

__global__ __launch_bounds__(256) void k_convW(const float* __restrict__ W2,
                                               const float* __restrict__ W3,
                                               unsigned short* __restrict__ W2b,
                                               unsigned short* __restrict__ W3b) {
    int idx = blockIdx.x * 256 + threadIdx.x;
    if (idx < 128 * 256) W2b[idx] = f2bf(W2[idx]);
    else {
        int j = idx - 128 * 256;
        if (j < 128 * 128) W3b[j] = f2bf(W3[j]);
    }
}

// ---- layer-1 input aggregation at F=6 (with clamp folded in), fp32 out ----

__global__ __launch_bounds__(256) void k_agg1(const float* __restrict__ x,
                                              const float* __restrict__ inputs,
                                              const int* __restrict__ cols,
                                              const float* __restrict__ vals,
                                              const int* __restrict__ nnzArr,
                                              const int* __restrict__ clampf,
                                              float* __restrict__ Xagg) {
    int idx = blockIdx.x * 256 + threadIdx.x;
    if (idx >= M_ * 6) return;
    int f = idx % 6;
    int r = idx / 6;
    int i = r % N_;
    int base = r - i;
    int n = nnzArr[i];
    float s = 0.f;
    for (int k = 0; k < n; ++k) {
        int c = cols[i * MAXNNZ + k];
        float val;
        if (f < 3 && clampf[c]) val = inputs[(size_t)(base + c) * 3 + f];
        else val = x[(size_t)(base + c) * 6 + f];
        s += vals[i * MAXNNZ + k] * val;
    }
    Xagg[idx] = s;
}

// ---- layer 1 linear: H1 = relu(Xagg @ W1^T + rowsum*b1), bf16 out ----

__global__ __launch_bounds__(256) void k_gemm1(const float* __restrict__ Xagg,
                                               const float* __restrict__ W1,
                                               const float* __restrict__ b1,
                                               const float* __restrict__ rowsum,
                                               unsigned short* __restrict__ H1) {
    __shared__ float W1s[256 * 6];
    __shared__ float b1s[256];
    int tid = threadIdx.x;
    for (int t = tid; t < 256 * 6; t += 256) W1s[t] = W1[t];
    b1s[tid] = b1[tid];
    __syncthreads();

    int idx = blockIdx.x * 256 + tid;
    int r = idx >> 5;
    int cg = idx & 31;
    int i = r % N_;
    float xa[6];
#pragma unroll
    for (int k = 0; k < 6; ++k) xa[k] = Xagg[(size_t)r * 6 + k];
    float rs = rowsum[i];
    us8 o;
#pragma unroll
    for (int c8 = 0; c8 < 8; ++c8) {
        int c = cg * 8 + c8;
        float s = rs * b1s[c];
#pragma unroll
        for (int k = 0; k < 6; ++k) s += xa[k] * W1s[c * 6 + k];
        o[c8] = f2bf(fmaxf(s, 0.f));
    }
    *(us8*)(H1 + (size_t)r * 256 + cg * 8) = o;
}

// ---- MFMA GEMM: C[M,128] = H[M,K](bf16) @ W[128,K](bf16)^T + bias, bf16 out ----

template <int K>
__global__ __launch_bounds__(256) void k_gemm_mfma(const unsigned short* __restrict__ H,
                                                   const unsigned short* __restrict__ Wb,
                                                   const float* __restrict__ bias,
                                                   unsigned short* __restrict__ C) {
    int tid = threadIdx.x;
    int lane = tid & 63;
    int wave = tid >> 6;
    int r0 = blockIdx.x * 64 + wave * 16;
    int lrow = lane & 15;
    int kgrp = lane >> 4;  // 0..3

    const unsigned short* Arow = H + (size_t)(r0 + lrow) * K + kgrp * 8;

    f32x4 acc[8];
#pragma unroll
    for (int j = 0; j < 8; ++j) acc[j] = (f32x4){0.f, 0.f, 0.f, 0.f};

    constexpr int NS = K / 32;
    bf16x8 a_cur = ld_bf8(Arow);
#pragma unroll
    for (int s = 0; s < NS; ++s) {
        bf16x8 a_next = a_cur;
        if (s + 1 < NS) a_next = ld_bf8(Arow + (s + 1) * 32);
#pragma unroll
        for (int j = 0; j < 8; ++j) {
            bf16x8 b = ld_bf8(Wb + (size_t)(j * 16 + lrow) * K + s * 32 + kgrp * 8);
            acc[j] = __builtin_amdgcn_mfma_f32_16x16x32_bf16(a_cur, b, acc[j], 0, 0, 0);
        }
        a_cur = a_next;
    }

#pragma unroll
    for (int j = 0; j < 8; ++j) {
        int n = j * 16 + lrow;      // D: col = lane&15
        float bv = bias[n];
#pragma unroll
        for (int e = 0; e < 4; ++e) {
            int row = r0 + kgrp * 4 + e;  // D: row = 4*(lane>>4)+e
            C[(size_t)row * 128 + n] = f2bf(acc[j][e] + bv);
        }
    }
}

// ---- sparse aggregation at F=128, bf16 in/out, optional relu ----

__global__ __launch_bounds__(256) void k_aggF(const unsigned short* __restrict__ Z,
                                              const int* __restrict__ cols,
                                              const float* __restrict__ vals,
                                              const int* __restrict__ nnzArr,
                                              unsigned short* __restrict__ Out,
                                              int relu) {
    int idx = blockIdx.x * 256 + threadIdx.x;
    int fg = idx & 15;
    int r = idx >> 4;
    int i = r % N_;
    int base = r - i;
    int n = nnzArr[i];
    float acc[8];
#pragma unroll
    for (int e = 0; e < 8; ++e) acc[e] = 0.f;
    for (int k = 0; k < n; ++k) {
        int c = cols[i * MAXNNZ + k];
        float v = vals[i * MAXNNZ + k];
        us8 z = *(const us8*)(Z + (size_t)(base + c) * 128 + fg * 8);
#pragma unroll
        for (int e = 0; e < 8; ++e) acc[e] += v * bf2f(z[e]);
    }
    us8 o;
#pragma unroll
    for (int e = 0; e < 8; ++e) {
        float s = acc[e];
        if (relu) s = fmaxf(s, 0.f);
        o[e] = f2bf(s);
    }
    *(us8*)(Out + (size_t)r * 128 + fg * 8) = o;
}

// ---- layer 4 linear: T4[M,3] = H3 @ W4^T + b4, fp32 out ----

__global__ __launch_bounds__(256) void k_gemm4(const unsigned short* __restrict__ H3,
                                               const float* __restrict__ W4,
                                               const float* __restrict__ b4,
                                               float* __restrict__ T4) {
    __shared__ float W4s[128 * 3];
    int tid = threadIdx.x;
    for (int t = tid; t < 384; t += 256) {
        int c = t % 3, k = t / 3;
        W4s[t] = W4[c * 128 + k];
    }
    __syncthreads();

    int idx = blockIdx.x * 256 + tid;
    int r = idx >> 2;
    int q = idx & 3;
    float a0 = 0.f, a1 = 0.f, a2 = 0.f;
    const unsigned short* row = H3 + (size_t)r * 128;
#pragma unroll
    for (int t = 0; t < 4; ++t) {
        int k0 = t * 32 + q * 8;
        us8 z = *(const us8*)(row + k0);
#pragma unroll
        for (int e = 0; e < 8; ++e) {
            float f = bf2f(z[e]);
            int k = k0 + e;
            a0 += f * W4s[k * 3 + 0];
            a1 += f * W4s[k * 3 + 1];
            a2 += f * W4s[k * 3 + 2];
        }
    }
#pragma unroll
    for (int m = 1; m < 4; m <<= 1) {
        a0 += __shfl_xor(a0, m, 4);
        a1 += __shfl_xor(a1, m, 4);
        a2 += __shfl_xor(a2, m, 4);
    }
    if (q == 0) {
        T4[(size_t)r * 3 + 0] = a0 + b4[0];
        T4[(size_t)r * 3 + 1] = a1 + b4[1];
        T4[(size_t)r * 3 + 2] = a2 + b4[2];
    }
}

// ---- final aggregation at F=3 with output clamp, fp32 out ----

__global__ __launch_bounds__(256) void k_agg_out(const float* __restrict__ T4,
                                                 const float* __restrict__ inputs,
                                                 const int* __restrict__ cols,
                                                 const float* __restrict__ vals,
                                                 const int* __restrict__ nnzArr,
                                                 const int* __restrict__ clampf,
                                                 float* __restrict__ out) {
    int idx = blockIdx.x * 256 + threadIdx.x;
    if (idx >= M_ * 3) return;
    int f = idx % 3;
    int r = idx / 3;
    int i = r % N_;
    int base = r - i;
    if (clampf[i]) {
        out[idx] = inputs[(size_t)r * 3 + f];
        return;
    }
    int n = nnzArr[i];
    float s = 0.f;
    for (int k = 0; k < n; ++k) {
        int c = cols[i * MAXNNZ + k];
        s += vals[i * MAXNNZ + k] * T4[(size_t)(base + c) * 3 + f];
    }
    out[idx] = s;
}

// ---------------- launch ----------------

extern "C" void kernel_launch(void* const* d_in, const int* in_sizes, int n_in,
                              void* d_out, int out_size, void* d_ws, size_t ws_size,
                              hipStream_t stream) {
    const float* x      = (const float*)d_in[0];
    const float* inputs = (const float*)d_in[1];
    const float* A      = (const float*)d_in[2];
    const float* W1     = (const float*)d_in[3];
    const float* b1     = (const float*)d_in[4];
    const float* W2     = (const float*)d_in[5];
    const float* b2     = (const float*)d_in[6];
    const float* W3     = (const float*)d_in[7];
    const float* b3     = (const float*)d_in[8];
    const float* W4     = (const float*)d_in[9];
    const float* b4     = (const float*)d_in[10];
    const int* psel     = (const int*)d_in[11];
    const int* c1sel    = (const int*)d_in[12];
    const int* c2sel    = (const int*)d_in[13];
    int np = in_sizes[11], n1 = in_sizes[12], n2 = in_sizes[13];
    float* out = (float*)d_out;

    char* ws = (char*)d_ws;
    float* dinv            = (float*)(ws + 0);
    float* rowsum          = (float*)(ws + 3072);
    int*   nnzA            = (int*)(ws + 6144);
    int*   clampf          = (int*)(ws + 9216);
    int*   cols            = (int*)(ws + 12288);
    float* vals            = (float*)(ws + 61440);
    unsigned short* W2b    = (unsigned short*)(ws + 110592);
    unsigned short* W3b    = (unsigned short*)(ws + 176128);
    float* Xagg            = (float*)(ws + 208896);
    float* T4              = (float*)(ws + 1388544);
    unsigned short* H1     = (unsigned short*)(ws + 1978368);
    unsigned short* T2     = (unsigned short*)(ws + 27144192);
    unsigned short* H2     = (unsigned short*)(ws + 39727104);
    unsigned short* T3     = (unsigned short*)(ws + 52310016);
    unsigned short* H3     = (unsigned short*)(ws + 64892928);

    // graph build (tiny)
    k_build_deg<<<N_, 256, 0, stream>>>(A, dinv);
    k_build_sparse<<<192, 256, 0, stream>>>(A, dinv, cols, vals, nnzA, rowsum);
    k_clampflag<<<1, 768, 0, stream>>>(clampf, psel, np, c1sel, n1, c2sel, n2);
    k_convW<<<192, 256, 0, stream>>>(W2, W3, W2b, W3b);

    // layer 1: aggregate at F=6, then linear 6->256 with rowsum-scaled bias + relu
    k_agg1<<<(M_ * 6) / 256, 256, 0, stream>>>(x, inputs, cols, vals, nnzA, clampf, Xagg);
    k_gemm1<<<(M_ * 32) / 256, 256, 0, stream>>>(Xagg, W1, b1, rowsum, H1);

    // layer 2: MFMA GEMM 256->128, then aggregate + relu
    k_gemm_mfma<256><<<M_ / 64, 256, 0, stream>>>(H1, W2b, b2, T2);
    k_aggF<<<(M_ * 16) / 256, 256, 0, stream>>>(T2, cols, vals, nnzA, H2, 1);

    // layer 3: MFMA GEMM 128->128, then aggregate (no relu)
    k_gemm_mfma<128><<<M_ / 64, 256, 0, stream>>>(H2, W3b, b3, T3);
    k_aggF<<<(M_ * 16) / 256, 256, 0, stream>>>(T3, cols, vals, nnzA, H3, 0);

    // layer 4: linear 128->3, then aggregate at F=3 with output clamp
    k_gemm4<<<(M_ * 4) / 256, 256, 0, stream>>>(H3, W4, b4, T4);
    k_agg_out<<<(M_ * 3 + 255) / 256, 256, 0, stream>>>(T4, inputs, cols, vals, nnzA,
                                                        clampf, out);
}

// Round 5
// 93.196 us; speedup vs baseline: 5.7144x; 1.2185x over previous
//
#include <hip/hip_runtime.h>
#include <math.h>

#define B_ 64
#define NV_ 256
#define N_ 768
#define MAXNNZ 16
#define M_ (B_ * N_)   // 49152 rows

typedef unsigned short us8 __attribute__((ext_vector_type(8)));
typedef __bf16 bf16x8 __attribute__((ext_vector_type(8)));
typedef float f32x4 __attribute__((ext_vector_type(4)));

__device__ inline float bf2f(unsigned short u) {
    return __uint_as_float(((unsigned int)u) << 16);
}
__device__ inline unsigned short f2bf(float f) {
    unsigned int u = __float_as_uint(f);
    unsigned int r = u + 0x7fffu + ((u >> 16) & 1u);
    return (unsigned short)(r >> 16);
}
__device__ inline bf16x8 ld_bf8(const unsigned short* p) {
    us8 u = *(const us8*)p;
    return __builtin_bit_cast(bf16x8, u);
}

// ---------------- build normalized sparse adjacency ----------------

__global__ __launch_bounds__(256) void k_build_deg(const float* __restrict__ A,
                                                   float* __restrict__ dinv) {
    int i = blockIdx.x;
    float s = 0.f;
    for (int j = threadIdx.x; j < N_; j += 256) s += A[i * N_ + j];
    __shared__ float red[256];
    red[threadIdx.x] = s;
    __syncthreads();
    for (int off = 128; off > 0; off >>= 1) {
        if (threadIdx.x < off) red[threadIdx.x] += red[threadIdx.x + off];
        __syncthreads();
    }
    if (threadIdx.x == 0) {
        float deg = red[0];
        dinv[i] = (deg == 0.f) ? 0.f : 1.0f / sqrtf(deg);
    }
}

// one wave per row: ballot-compacted sparse extraction
__global__ __launch_bounds__(256) void k_build_sparse(const float* __restrict__ A,
                                                      const float* __restrict__ dinv,
                                                      int* __restrict__ cols,
                                                      float* __restrict__ vals,
                                                      int* __restrict__ nnzArr,
                                                      float* __restrict__ rowsum) {
    int wid = (blockIdx.x * 256 + threadIdx.x) >> 6;  // row
    int lane = threadIdx.x & 63;
    if (wid >= N_) return;
    int i = wid;
    float di = dinv[i];
    int cnt = 0;
    float rs = 0.f;
#pragma unroll
    for (int c0 = 0; c0 < N_; c0 += 64) {
        int c = c0 + lane;
        float a = A[(size_t)i * N_ + c];
        unsigned long long m = __ballot(a != 0.f);
        float v = 0.f;
        if (a != 0.f) {
            v = a * di * dinv[c];
            int pos = cnt + __popcll(m & ((1ull << lane) - 1ull));
            if (pos < MAXNNZ) {
                cols[i * MAXNNZ + pos] = c;
                vals[i * MAXNNZ + pos] = v;
            }
        }
        cnt += (int)__popcll(m);
        rs += v;
    }
#pragma unroll
    for (int o = 32; o > 0; o >>= 1) rs += __shfl_xor(rs, o);
    if (lane == 0) {
        nnzArr[i] = cnt;
        rowsum[i] = rs;
    }
}

__global__ void k_clampflag(int* __restrict__ flag, const int* __restrict__ p, int np,
                            const int* __restrict__ c1, int n1,
                            const int* __restrict__ c2, int n2) {
    int t = threadIdx.x;
    if (t < N_) flag[t] = 0;
    __syncthreads();
    if (t < np) flag[p[t]] = 1;
    else if (t - np < n1) flag[NV_ + c1[t - np]] = 1;
    else if (t - np - n1 < n2) flag[2 * NV_ + c2[t - np - n1]] = 1;
}

__global__ __launch_bounds__(256) void k_convW(const float* __restrict__ W2,
                                               const float* __restrict__ W3,
                                               unsigned short* __restrict__ W2b,
                                               unsigned short* __restrict__ W3b) {
    int idx = blockIdx.x * 256 + threadIdx.x;
    if (idx < 128 * 256) W2b[idx] = f2bf(W2[idx]);
    else {
        int j = idx - 128 * 256;
        if (j < 128 * 128) W3b[j] = f2bf(W3[j]);
    }
}

// ---- fused layers 1+2: agg(F=6) -> linear 6->256 + relu (LDS) -> MFMA 256->128 ----
// grid: M_/64 = 768 blocks; block handles 64 consecutive rows (one b, i0..i0+63)

#define P1 264  // 256 + 8 bf16 pad: row stride 528B = 33x16B, avoids bank conflicts

__global__ __launch_bounds__(256) void k_layer12(
    const float* __restrict__ x, const float* __restrict__ inputs,
    const int* __restrict__ cols, const float* __restrict__ vals,
    const int* __restrict__ nnzArr, const int* __restrict__ clampf,
    const float* __restrict__ rowsum, const float* __restrict__ W1,
    const float* __restrict__ b1, const unsigned short* __restrict__ W2b,
    const float* __restrict__ b2, unsigned short* __restrict__ T2) {
    __shared__ float Xs[64][6];
    __shared__ float W1s[256 * 6];
    __shared__ float b1s[256];
    __shared__ unsigned short H1s[64][P1];

    int tid = threadIdx.x;
    int blk = blockIdx.x;
    int b = blk / 12, i0 = (blk % 12) * 64;
    int base = b * N_;

    for (int t = tid; t < 256 * 6; t += 256) W1s[t] = W1[t];
    b1s[tid] = b1[tid];

    // stage 1: aggregated input features (with clamp), 64 rows x 6
    for (int t = tid; t < 64 * 6; t += 256) {
        int f = t % 6, ro = t / 6;
        int i = i0 + ro;
        int n = nnzArr[i];
        float s = 0.f;
        for (int k = 0; k < n; ++k) {
            int c = cols[i * MAXNNZ + k];
            float val = (f < 3 && clampf[c]) ? inputs[(size_t)(base + c) * 3 + f]
                                             : x[(size_t)(base + c) * 6 + f];
            s += vals[i * MAXNNZ + k] * val;
        }
        Xs[ro][f] = s;
    }
    __syncthreads();

    // stage 2: H1 tile = relu(Xs @ W1^T + rowsum*b1), 64 x 256 bf16 in LDS
    for (int t = tid; t < 64 * 32; t += 256) {
        int cg = t & 31, ro = t >> 5;
        int i = i0 + ro;
        float rs = rowsum[i];
        float xa[6];
#pragma unroll
        for (int k = 0; k < 6; ++k) xa[k] = Xs[ro][k];
        us8 o;
#pragma unroll
        for (int c8 = 0; c8 < 8; ++c8) {
            int c = cg * 8 + c8;
            float s = rs * b1s[c];
#pragma unroll
            for (int k = 0; k < 6; ++k) s += xa[k] * W1s[c * 6 + k];
            o[c8] = f2bf(fmaxf(s, 0.f));
        }
        *(us8*)&H1s[ro][cg * 8] = o;
    }
    __syncthreads();

    // stage 3: MFMA 64x128 = H1s(64x256) @ W2^T
    int lane = tid & 63, wave = tid >> 6;
    int lrow = lane & 15, kgrp = lane >> 4;

    f32x4 acc[8];
#pragma unroll
    for (int j = 0; j < 8; ++j) acc[j] = (f32x4){0.f, 0.f, 0.f, 0.f};

#pragma unroll
    for (int s = 0; s < 8; ++s) {
        bf16x8 a = __builtin_bit_cast(
            bf16x8, *(const us8*)&H1s[wave * 16 + lrow][s * 32 + kgrp * 8]);
#pragma unroll
        for (int j = 0; j < 8; ++j) {
            bf16x8 bb = ld_bf8(W2b + (size_t)(j * 16 + lrow) * 256 + s * 32 + kgrp * 8);
            acc[j] = __builtin_amdgcn_mfma_f32_16x16x32_bf16(a, bb, acc[j], 0, 0, 0);
        }
    }

    int r0 = blk * 64 + wave * 16;
#pragma unroll
    for (int j = 0; j < 8; ++j) {
        int n = j * 16 + lrow;
        float bv = b2[n];
#pragma unroll
        for (int e = 0; e < 4; ++e) {
            int row = r0 + kgrp * 4 + e;
            T2[(size_t)row * 128 + n] = f2bf(acc[j][e] + bv);
        }
    }
}

// ---- fused layer 3: relu(agg(T2)) in LDS -> MFMA 128->128 -> T3 ----

#define P2 136  // 128 + 8 pad

__global__ __launch_bounds__(256) void k_layer3(
    const unsigned short* __restrict__ T2, const int* __restrict__ cols,
    const float* __restrict__ vals, const int* __restrict__ nnzArr,
    const unsigned short* __restrict__ W3b, const float* __restrict__ b3,
    unsigned short* __restrict__ T3) {
    __shared__ unsigned short H2s[64][P2];

    int tid = threadIdx.x;
    int blk = blockIdx.x;
    int i0 = (blk % 12) * 64;
    int base = (blk / 12) * N_;

    // stage: H2 tile = relu(agg(T2)), 64 x 128 bf16
    for (int t = tid; t < 64 * 16; t += 256) {
        int cg = t & 15, ro = t >> 4;
        int i = i0 + ro;
        int n = nnzArr[i];
        float acc[8];
#pragma unroll
        for (int e = 0; e < 8; ++e) acc[e] = 0.f;
        for (int k = 0; k < n; ++k) {
            int c = cols[i * MAXNNZ + k];
            float v = vals[i * MAXNNZ + k];
            us8 z = *(const us8*)(T2 + (size_t)(base + c) * 128 + cg * 8);
#pragma unroll
            for (int e = 0; e < 8; ++e) acc[e] += v * bf2f(z[e]);
        }
        us8 o;
#pragma unroll
        for (int e = 0; e < 8; ++e) o[e] = f2bf(fmaxf(acc[e], 0.f));
        *(us8*)&H2s[ro][cg * 8] = o;
    }
    __syncthreads();

    int lane = tid & 63, wave = tid >> 6;
    int lrow = lane & 15, kgrp = lane >> 4;

    f32x4 acc[8];
#pragma unroll
    for (int j = 0; j < 8; ++j) acc[j] = (f32x4){0.f, 0.f, 0.f, 0.f};

#pragma unroll
    for (int s = 0; s < 4; ++s) {
        bf16x8 a = __builtin_bit_cast(
            bf16x8, *(const us8*)&H2s[wave * 16 + lrow][s * 32 + kgrp * 8]);
#pragma unroll
        for (int j = 0; j < 8; ++j) {
            bf16x8 bb = ld_bf8(W3b + (size_t)(j * 16 + lrow) * 128 + s * 32 + kgrp * 8);
            acc[j] = __builtin_amdgcn_mfma_f32_16x16x32_bf16(a, bb, acc[j], 0, 0, 0);
        }
    }

    int r0 = blk * 64 + wave * 16;
#pragma unroll
    for (int j = 0; j < 8; ++j) {
        int n = j * 16 + lrow;
        float bv = b3[n];
#pragma unroll
        for (int e = 0; e < 4; ++e) {
            int row = r0 + kgrp * 4 + e;
            T3[(size_t)row * 128 + n] = f2bf(acc[j][e] + bv);
        }
    }
}

// ---- fused layer 4: agg(T3) in LDS -> linear 128->3 -> T4 (fp32) ----

__global__ __launch_bounds__(256) void k_layer4(
    const unsigned short* __restrict__ T3, const int* __restrict__ cols,
    const float* __restrict__ vals, const int* __restrict__ nnzArr,
    const float* __restrict__ W4, const float* __restrict__ b4,
    float* __restrict__ T4) {
    __shared__ unsigned short H3s[64][P2];
    __shared__ float W4s[128 * 3];

    int tid = threadIdx.x;
    int blk = blockIdx.x;
    int i0 = (blk % 12) * 64;
    int base = (blk / 12) * N_;

    for (int t = tid; t < 384; t += 256) {
        int c = t % 3, k = t / 3;
        W4s[t] = W4[c * 128 + k];
    }

    // stage: H3 tile = agg(T3), 64 x 128 bf16
    for (int t = tid; t < 64 * 16; t += 256) {
        int cg = t & 15, ro = t >> 4;
        int i = i0 + ro;
        int n = nnzArr[i];
        float acc[8];
#pragma unroll
        for (int e = 0; e < 8; ++e) acc[e] = 0.f;
        for (int k = 0; k < n; ++k) {
            int c = cols[i * MAXNNZ + k];
            float v = vals[i * MAXNNZ + k];
            us8 z = *(const us8*)(T3 + (size_t)(base + c) * 128 + cg * 8);
#pragma unroll
            for (int e = 0; e < 8; ++e) acc[e] += v * bf2f(z[e]);
        }
        us8 o;
#pragma unroll
        for (int e = 0; e < 8; ++e) o[e] = f2bf(acc[e]);
        *(us8*)&H3s[ro][cg * 8] = o;
    }
    __syncthreads();

    // dot: 4 lanes per row, each covers 32 k's; shuffle-reduce
    int ro = tid >> 2, q = tid & 3;
    float a0 = 0.f, a1 = 0.f, a2 = 0.f;
#pragma unroll
    for (int t = 0; t < 4; ++t) {
        int k0 = q * 32 + t * 8;
        us8 z = *(const us8*)&H3s[ro][k0];
#pragma unroll
        for (int e = 0; e < 8; ++e) {
            float f = bf2f(z[e]);
            int k = k0 + e;
            a0 += f * W4s[k * 3 + 0];
            a1 += f * W4s[k * 3 + 1];
            a2 += f * W4s[k * 3 + 2];
        }
    }
#pragma unroll
    for (int m = 1; m < 4; m <<= 1) {
        a0 += __shfl_xor(a0, m, 4);
        a1 += __shfl_xor(a1, m, 4);
        a2 += __shfl_xor(a2, m, 4);
    }
    if (q == 0) {
        int r = blk * 64 + ro;
        T4[(size_t)r * 3 + 0] = a0 + b4[0];
        T4[(size_t)r * 3 + 1] = a1 + b4[1];
        T4[(size_t)r * 3 + 2] = a2 + b4[2];
    }
}

// ---- final aggregation at F=3 with output clamp, fp32 out ----

__global__ __launch_bounds__(256) void k_agg_out(const float* __restrict__ T4,
                                                 const float* __restrict__ inputs,
                                                 const int* __restrict__ cols,
                                                 const float* __restrict__ vals,
                                                 const int* __restrict__ nnzArr,
                                                 const int* __restrict__ clampf,
                                                 float* __restrict__ out) {
    int idx = blockIdx.x * 256 + threadIdx.x;
    if (idx >= M_ * 3) return;
    int f = idx % 3;
    int r = idx / 3;
    int i = r % N_;
    int base = r - i;
    if (clampf[i]) {
        out[idx] = inputs[(size_t)r * 3 + f];
        return;
    }
    int n = nnzArr[i];
    float s = 0.f;
    for (int k = 0; k < n; ++k) {
        int c = cols[i * MAXNNZ + k];
        s += vals[i * MAXNNZ + k] * T4[(size_t)(base + c) * 3 + f];
    }
    out[idx] = s;
}

// ---------------- launch ----------------

extern "C" void kernel_launch(void* const* d_in, const int* in_sizes, int n_in,
                              void* d_out, int out_size, void* d_ws, size_t ws_size,
                              hipStream_t stream) {
    const float* x      = (const float*)d_in[0];
    const float* inputs = (const float*)d_in[1];
    const float* A      = (const float*)d_in[2];
    const float* W1     = (const float*)d_in[3];
    const float* b1     = (const float*)d_in[4];
    const float* W2     = (const float*)d_in[5];
    const float* b2     = (const float*)d_in[6];
    const float* W3     = (const float*)d_in[7];
    const float* b3     = (const float*)d_in[8];
    const float* W4     = (const float*)d_in[9];
    const float* b4     = (const float*)d_in[10];
    const int* psel     = (const int*)d_in[11];
    const int* c1sel    = (const int*)d_in[12];
    const int* c2sel    = (const int*)d_in[13];
    int np = in_sizes[11], n1 = in_sizes[12], n2 = in_sizes[13];
    float* out = (float*)d_out;

    char* ws = (char*)d_ws;
    float* dinv            = (float*)(ws + 0);
    float* rowsum          = (float*)(ws + 3072);
    int*   nnzA            = (int*)(ws + 6144);
    int*   clampf          = (int*)(ws + 9216);
    int*   cols            = (int*)(ws + 12288);
    float* vals            = (float*)(ws + 61440);
    unsigned short* W2b    = (unsigned short*)(ws + 110592);
    unsigned short* W3b    = (unsigned short*)(ws + 176128);
    float* T4              = (float*)(ws + 1388544);
    unsigned short* T2     = (unsigned short*)(ws + 27144192);
    unsigned short* T3     = (unsigned short*)(ws + 52310016);

    // graph build (tiny)
    k_build_deg<<<N_, 256, 0, stream>>>(A, dinv);
    k_build_sparse<<<192, 256, 0, stream>>>(A, dinv, cols, vals, nnzA, rowsum);
    k_clampflag<<<1, 768, 0, stream>>>(clampf, psel, np, c1sel, n1, c2sel, n2);
    k_convW<<<192, 256, 0, stream>>>(W2, W3, W2b, W3b);

    // fused layers
    k_layer12<<<M_ / 64, 256, 0, stream>>>(x, inputs, cols, vals, nnzA, clampf, rowsum,
                                           W1, b1, W2b, b2, T2);
    k_layer3<<<M_ / 64, 256, 0, stream>>>(T2, cols, vals, nnzA, W3b, b3, T3);
    k_layer4<<<M_ / 64, 256, 0, stream>>>(T3, cols, vals, nnzA, W4, b4, T4);
    k_agg_out<<<(M_ * 3 + 255) / 256, 256, 0, stream>>>(T4, inputs, cols, vals, nnzA,
                                                        clampf, out);
}

// Round 7
// 81.547 us; speedup vs baseline: 6.5307x; 1.1428x over previous
//
#include <hip/hip_runtime.h>
#include <math.h>

#define B_ 64
#define NV_ 256
#define N_ 768
#define MAXNNZ 16
#define M_ (B_ * N_)   // 49152 rows

typedef unsigned short us8 __attribute__((ext_vector_type(8)));
typedef unsigned short us4 __attribute__((ext_vector_type(4)));
typedef __bf16 bf16x8 __attribute__((ext_vector_type(8)));
typedef float f32x4 __attribute__((ext_vector_type(4)));

__device__ inline float bf2f(unsigned short u) {
    return __uint_as_float(((unsigned int)u) << 16);
}
__device__ inline unsigned short f2bf(float f) {
    unsigned int u = __float_as_uint(f);
    unsigned int r = u + 0x7fffu + ((u >> 16) & 1u);
    return (unsigned short)(r >> 16);
}
__device__ inline bf16x8 ld_bf8(const unsigned short* p) {
    us8 u = *(const us8*)p;
    return __builtin_bit_cast(bf16x8, u);
}

// ---------------- merged prep: sparse A_norm + clamp flags + W->bf16 ----------------

__global__ __launch_bounds__(256) void k_prep(
    const float* __restrict__ A, const float* __restrict__ W2,
    const float* __restrict__ W3, const int* __restrict__ psel, int np,
    const int* __restrict__ c1, int n1, const int* __restrict__ c2, int n2,
    int* __restrict__ cols, float* __restrict__ vals, int* __restrict__ nnzArr,
    float* __restrict__ rowsum, int* __restrict__ clampf,
    unsigned short* __restrict__ W2b, unsigned short* __restrict__ W3b) {
    __shared__ int wc[4][MAXNNZ];
    __shared__ float wa[4][MAXNNZ];
    int blk = blockIdx.x, tid = threadIdx.x;

    if (blk < 192) {
        int wave = tid >> 6, lane = tid & 63;
        int i = blk * 4 + wave;
        int cnt = 0;
        float deg = 0.f;
#pragma unroll
        for (int c0 = 0; c0 < N_; c0 += 64) {
            float a = A[(size_t)i * N_ + c0 + lane];
            deg += a;
            unsigned long long m = __ballot(a != 0.f);
            if (a != 0.f) {
                int pos = cnt + __popcll(m & ((1ull << lane) - 1ull));
                if (pos < MAXNNZ) {
                    wc[wave][pos] = c0 + lane;
                    wa[wave][pos] = a;
                }
            }
            cnt += (int)__popcll(m);
        }
#pragma unroll
        for (int o = 32; o > 0; o >>= 1) deg += __shfl_xor(deg, o);
        float dinv_i = (deg == 0.f) ? 0.f : 1.0f / sqrtf(deg);
        __syncthreads();
        int nn = cnt < MAXNNZ ? cnt : MAXNNZ;
        float rs = 0.f;
        for (int p = 0; p < nn; ++p) {
            int c = wc[wave][p];
            float dc = 0.f;
#pragma unroll
            for (int c0 = 0; c0 < N_; c0 += 64) dc += A[(size_t)c * N_ + c0 + lane];
#pragma unroll
            for (int o = 32; o > 0; o >>= 1) dc += __shfl_xor(dc, o);
            float dinv_c = (dc == 0.f) ? 0.f : 1.0f / sqrtf(dc);
            float v = wa[wave][p] * dinv_i * dinv_c;
            rs += v;
            if (lane == 0) {
                cols[i * MAXNNZ + p] = c;
                vals[i * MAXNNZ + p] = v;
            }
        }
        if (lane == 0) {
            nnzArr[i] = cnt;
            rowsum[i] = rs;
        }
    } else if (blk < 384) {
        int idx = (blk - 192) * 256 + tid;
        if (idx < 128 * 256) W2b[idx] = f2bf(W2[idx]);
        else W3b[idx - 128 * 256] = f2bf(W3[idx - 128 * 256]);
    } else {
        clampf[tid] = 0;
        clampf[tid + 256] = 0;
        clampf[tid + 512] = 0;
        __syncthreads();
        if (tid < np) clampf[psel[tid]] = 1;
        else if (tid - np < n1) clampf[NV_ + c1[tid - np]] = 1;
        else if (tid - np - n1 < n2) clampf[2 * NV_ + c2[tid - np - n1]] = 1;
    }
}

// ---- fused layers 1+2: agg(F=6) -> 6->256 linear+relu (registers) -> MFMA 256->128 ----

__global__ __launch_bounds__(256) void k_layer12(
    const float* __restrict__ x, const float* __restrict__ inputs,
    const int* __restrict__ cols, const float* __restrict__ vals,
    const int* __restrict__ nnzArr, const int* __restrict__ clampf,
    const float* __restrict__ rowsum, const float* __restrict__ W1,
    const float* __restrict__ b1, const unsigned short* __restrict__ W2b,
    const float* __restrict__ b2, unsigned short* __restrict__ T2) {
    __shared__ float Xs[64][6];
    __shared__ float W1T[6][256];
    __shared__ float b1s[256];

    int tid = threadIdx.x;
    int blk = blockIdx.x;
    int i0 = (blk % 12) * 64;
    int base = (blk / 12) * N_;
    int wave = tid >> 6, lane = tid & 63;
    int lrow = lane & 15, kgrp = lane >> 4;

    for (int t = tid; t < 1536; t += 256) {
        int k = t >> 8, c = t & 255;
        W1T[k][c] = W1[c * 6 + k];
    }
    b1s[tid] = b1[tid];

    for (int t = lane; t < 96; t += 64) {
        int f = t % 6, ro = t / 6;
        int i = i0 + wave * 16 + ro;
        int n = nnzArr[i];
        float s = 0.f;
        for (int k = 0; k < n; ++k) {
            int c = cols[i * MAXNNZ + k];
            float val = (f < 3 && clampf[c]) ? inputs[(size_t)(base + c) * 3 + f]
                                             : x[(size_t)(base + c) * 6 + f];
            s += vals[i * MAXNNZ + k] * val;
        }
        Xs[wave * 16 + ro][f] = s;
    }
    __syncthreads();

    int i = i0 + wave * 16 + lrow;   // node index
    size_t g = (size_t)(base + i);   // global row (FIX: batch offset)
    float rs = rowsum[i];
    float xa[6];
#pragma unroll
    for (int k = 0; k < 6; ++k) xa[k] = Xs[wave * 16 + lrow][k];

    f32x4 acc[8];
#pragma unroll
    for (int j = 0; j < 8; ++j) acc[j] = (f32x4){0.f, 0.f, 0.f, 0.f};

#pragma unroll
    for (int s = 0; s < 8; ++s) {
        int c0 = s * 32 + kgrp * 8;
        float h[8];
        f32x4 bv0 = *(const f32x4*)&b1s[c0];
        f32x4 bv1 = *(const f32x4*)&b1s[c0 + 4];
#pragma unroll
        for (int e = 0; e < 4; ++e) {
            h[e] = rs * bv0[e];
            h[4 + e] = rs * bv1[e];
        }
#pragma unroll
        for (int k = 0; k < 6; ++k) {
            f32x4 w0 = *(const f32x4*)&W1T[k][c0];
            f32x4 w1 = *(const f32x4*)&W1T[k][c0 + 4];
#pragma unroll
            for (int e = 0; e < 4; ++e) {
                h[e] += xa[k] * w0[e];
                h[4 + e] += xa[k] * w1[e];
            }
        }
        us8 o;
#pragma unroll
        for (int e = 0; e < 8; ++e) o[e] = f2bf(fmaxf(h[e], 0.f));
        bf16x8 af = __builtin_bit_cast(bf16x8, o);
#pragma unroll
        for (int j = 0; j < 8; ++j) {
            bf16x8 w = ld_bf8(W2b + (size_t)(j * 16 + lrow) * 256 + c0);
            acc[j] = __builtin_amdgcn_mfma_f32_16x16x32_bf16(w, af, acc[j], 0, 0, 0);
        }
    }

#pragma unroll
    for (int j = 0; j < 8; ++j) {
        f32x4 bv = *(const f32x4*)&b2[j * 16 + kgrp * 4];
        us4 o;
#pragma unroll
        for (int e = 0; e < 4; ++e) o[e] = f2bf(acc[j][e] + bv[e]);
        *(us4*)(T2 + g * 128 + j * 16 + kgrp * 4) = o;
    }
}

// ---- fused layer 3: relu(agg(T2)) into registers -> MFMA 128->128 -> T3 ----

__global__ __launch_bounds__(256) void k_layer3(
    const unsigned short* __restrict__ T2, const int* __restrict__ cols,
    const float* __restrict__ vals, const int* __restrict__ nnzArr,
    const unsigned short* __restrict__ W3b, const float* __restrict__ b3,
    unsigned short* __restrict__ T3) {
    int tid = threadIdx.x;
    int blk = blockIdx.x;
    int i0 = (blk % 12) * 64;
    int base = (blk / 12) * N_;
    int wave = tid >> 6, lane = tid & 63;
    int lrow = lane & 15, kgrp = lane >> 4;
    int i = i0 + wave * 16 + lrow;
    size_t g = (size_t)(base + i);   // FIX: batch offset
    int n = nnzArr[i];
    if (n > MAXNNZ) n = MAXNNZ;

    float fa[4][8];
#pragma unroll
    for (int s = 0; s < 4; ++s)
#pragma unroll
        for (int e = 0; e < 8; ++e) fa[s][e] = 0.f;

    for (int k = 0; k < n; ++k) {
        int c = cols[i * MAXNNZ + k];
        float v = vals[i * MAXNNZ + k];
        const unsigned short* p = T2 + (size_t)(base + c) * 128 + kgrp * 8;
#pragma unroll
        for (int s = 0; s < 4; ++s) {
            us8 z = *(const us8*)(p + s * 32);
#pragma unroll
            for (int e = 0; e < 8; ++e) fa[s][e] += v * bf2f(z[e]);
        }
    }

    bf16x8 af[4];
#pragma unroll
    for (int s = 0; s < 4; ++s) {
        us8 o;
#pragma unroll
        for (int e = 0; e < 8; ++e) o[e] = f2bf(fmaxf(fa[s][e], 0.f));
        af[s] = __builtin_bit_cast(bf16x8, o);
    }

    f32x4 acc[8];
#pragma unroll
    for (int j = 0; j < 8; ++j) acc[j] = (f32x4){0.f, 0.f, 0.f, 0.f};
#pragma unroll
    for (int s = 0; s < 4; ++s) {
#pragma unroll
        for (int j = 0; j < 8; ++j) {
            bf16x8 w = ld_bf8(W3b + (size_t)(j * 16 + lrow) * 128 + s * 32 + kgrp * 8);
            acc[j] = __builtin_amdgcn_mfma_f32_16x16x32_bf16(w, af[s], acc[j], 0, 0, 0);
        }
    }

#pragma unroll
    for (int j = 0; j < 8; ++j) {
        f32x4 bv = *(const f32x4*)&b3[j * 16 + kgrp * 4];
        us4 o;
#pragma unroll
        for (int e = 0; e < 4; ++e) o[e] = f2bf(acc[j][e] + bv[e]);
        *(us4*)(T3 + g * 128 + j * 16 + kgrp * 4) = o;
    }
}

// ---- fused layer 4: agg(T3) into registers -> 128->3 dot -> T4 (fp32) ----

__global__ __launch_bounds__(256) void k_layer4(
    const unsigned short* __restrict__ T3, const int* __restrict__ cols,
    const float* __restrict__ vals, const int* __restrict__ nnzArr,
    const float* __restrict__ W4, const float* __restrict__ b4,
    float* __restrict__ T4) {
    int tid = threadIdx.x;
    int blk = blockIdx.x;
    int i0 = (blk % 12) * 64;
    int base = (blk / 12) * N_;
    int wave = tid >> 6, lane = tid & 63;
    int lrow = lane & 15, kgrp = lane >> 4;
    int i = i0 + wave * 16 + lrow;
    size_t g = (size_t)(base + i);   // FIX: batch offset
    int n = nnzArr[i];
    if (n > MAXNNZ) n = MAXNNZ;

    float fa[4][8];
#pragma unroll
    for (int s = 0; s < 4; ++s)
#pragma unroll
        for (int e = 0; e < 8; ++e) fa[s][e] = 0.f;

    for (int k = 0; k < n; ++k) {
        int c = cols[i * MAXNNZ + k];
        float v = vals[i * MAXNNZ + k];
        const unsigned short* p = T3 + (size_t)(base + c) * 128 + kgrp * 8;
#pragma unroll
        for (int s = 0; s < 4; ++s) {
            us8 z = *(const us8*)(p + s * 32);
#pragma unroll
            for (int e = 0; e < 8; ++e) fa[s][e] += v * bf2f(z[e]);
        }
    }

    float ad[3] = {0.f, 0.f, 0.f};
#pragma unroll
    for (int d = 0; d < 3; ++d) {
#pragma unroll
        for (int s = 0; s < 4; ++s) {
            int c0 = s * 32 + kgrp * 8;
            f32x4 w0 = *(const f32x4*)&W4[d * 128 + c0];
            f32x4 w1 = *(const f32x4*)&W4[d * 128 + c0 + 4];
#pragma unroll
            for (int e = 0; e < 4; ++e) {
                ad[d] += fa[s][e] * w0[e];
                ad[d] += fa[s][4 + e] * w1[e];
            }
        }
        ad[d] += __shfl_xor(ad[d], 16);
        ad[d] += __shfl_xor(ad[d], 32);
    }
    if (kgrp == 0) {
        T4[g * 3 + 0] = ad[0] + b4[0];
        T4[g * 3 + 1] = ad[1] + b4[1];
        T4[g * 3 + 2] = ad[2] + b4[2];
    }
}

// ---- final aggregation at F=3 with output clamp, fp32 out ----

__global__ __launch_bounds__(256) void k_agg_out(const float* __restrict__ T4,
                                                 const float* __restrict__ inputs,
                                                 const int* __restrict__ cols,
                                                 const float* __restrict__ vals,
                                                 const int* __restrict__ nnzArr,
                                                 const int* __restrict__ clampf,
                                                 float* __restrict__ out) {
    int idx = blockIdx.x * 256 + threadIdx.x;
    if (idx >= M_ * 3) return;
    int f = idx % 3;
    int r = idx / 3;
    int i = r % N_;
    int base = r - i;
    if (clampf[i]) {
        out[idx] = inputs[(size_t)r * 3 + f];
        return;
    }
    int n = nnzArr[i];
    if (n > MAXNNZ) n = MAXNNZ;
    float s = 0.f;
    for (int k = 0; k < n; ++k) {
        int c = cols[i * MAXNNZ + k];
        s += vals[i * MAXNNZ + k] * T4[(size_t)(base + c) * 3 + f];
    }
    out[idx] = s;
}

// ---------------- launch ----------------

extern "C" void kernel_launch(void* const* d_in, const int* in_sizes, int n_in,
                              void* d_out, int out_size, void* d_ws, size_t ws_size,
                              hipStream_t stream) {
    const float* x      = (const float*)d_in[0];
    const float* inputs = (const float*)d_in[1];
    const float* A      = (const float*)d_in[2];
    const float* W1     = (const float*)d_in[3];
    const float* b1     = (const float*)d_in[4];
    const float* W2     = (const float*)d_in[5];
    const float* b2     = (const float*)d_in[6];
    const float* W3     = (const float*)d_in[7];
    const float* b3     = (const float*)d_in[8];
    const float* W4     = (const float*)d_in[9];
    const float* b4     = (const float*)d_in[10];
    const int* psel     = (const int*)d_in[11];
    const int* c1sel    = (const int*)d_in[12];
    const int* c2sel    = (const int*)d_in[13];
    int np = in_sizes[11], n1 = in_sizes[12], n2 = in_sizes[13];
    float* out = (float*)d_out;

    char* ws = (char*)d_ws;
    float* rowsum          = (float*)(ws + 3072);
    int*   nnzA            = (int*)(ws + 6144);
    int*   clampf          = (int*)(ws + 9216);
    int*   cols            = (int*)(ws + 12288);
    float* vals            = (float*)(ws + 61440);
    unsigned short* W2b    = (unsigned short*)(ws + 110592);
    unsigned short* W3b    = (unsigned short*)(ws + 176128);
    float* T4              = (float*)(ws + 1388544);
    unsigned short* T2     = (unsigned short*)(ws + 27144192);
    unsigned short* T3     = (unsigned short*)(ws + 52310016);

    k_prep<<<385, 256, 0, stream>>>(A, W2, W3, psel, np, c1sel, n1, c2sel, n2,
                                    cols, vals, nnzA, rowsum, clampf, W2b, W3b);

    k_layer12<<<M_ / 64, 256, 0, stream>>>(x, inputs, cols, vals, nnzA, clampf, rowsum,
                                           W1, b1, W2b, b2, T2);
    k_layer3<<<M_ / 64, 256, 0, stream>>>(T2, cols, vals, nnzA, W3b, b3, T3);
    k_layer4<<<M_ / 64, 256, 0, stream>>>(T3, cols, vals, nnzA, W4, b4, T4);
    k_agg_out<<<(M_ * 3 + 255) / 256, 256, 0, stream>>>(T4, inputs, cols, vals, nnzA,
                                                        clampf, out);
}

// Round 9
// 70.092 us; speedup vs baseline: 7.5980x; 1.1634x over previous
//
#include <hip/hip_runtime.h>
#include <math.h>

#define B_ 64
#define NV_ 256
#define N_ 768
#define MAXNNZ 16
#define M_ (B_ * N_)   // 49152 rows

typedef unsigned short us8 __attribute__((ext_vector_type(8)));
typedef unsigned short us4 __attribute__((ext_vector_type(4)));
typedef __bf16 bf16x8 __attribute__((ext_vector_type(8)));
typedef float f32x4 __attribute__((ext_vector_type(4)));

__device__ inline float bf2f(unsigned short u) {
    return __uint_as_float(((unsigned int)u) << 16);
}
__device__ inline unsigned short f2bf(float f) {
    unsigned int u = __float_as_uint(f);
    unsigned int r = u + 0x7fffu + ((u >> 16) & 1u);
    return (unsigned short)(r >> 16);
}
__device__ inline bf16x8 ld_bf8(const unsigned short* p) {
    us8 u = *(const us8*)p;
    return __builtin_bit_cast(bf16x8, u);
}

// ---------------- merged prep: sparse A_norm + clamp flags + W->bf16 ----------------

__global__ __launch_bounds__(256) void k_prep(
    const float* __restrict__ A, const float* __restrict__ W2,
    const float* __restrict__ W3, const int* __restrict__ psel, int np,
    const int* __restrict__ c1, int n1, const int* __restrict__ c2, int n2,
    int* __restrict__ cols, float* __restrict__ vals, int* __restrict__ nnzArr,
    float* __restrict__ rowsum, int* __restrict__ clampf,
    unsigned short* __restrict__ W2b, unsigned short* __restrict__ W3b) {
    __shared__ int wc[4][MAXNNZ];
    __shared__ float wa[4][MAXNNZ];
    int blk = blockIdx.x, tid = threadIdx.x;

    if (blk < 192) {
        int wave = tid >> 6, lane = tid & 63;
        int i = blk * 4 + wave;
        int cnt = 0;
        float deg = 0.f;
#pragma unroll
        for (int c0 = 0; c0 < N_; c0 += 64) {
            float a = A[(size_t)i * N_ + c0 + lane];
            deg += a;
            unsigned long long m = __ballot(a != 0.f);
            if (a != 0.f) {
                int pos = cnt + __popcll(m & ((1ull << lane) - 1ull));
                if (pos < MAXNNZ) {
                    wc[wave][pos] = c0 + lane;
                    wa[wave][pos] = a;
                }
            }
            cnt += (int)__popcll(m);
        }
#pragma unroll
        for (int o = 32; o > 0; o >>= 1) deg += __shfl_xor(deg, o);
        float dinv_i = (deg == 0.f) ? 0.f : 1.0f / sqrtf(deg);
        __syncthreads();
        int nn = cnt < MAXNNZ ? cnt : MAXNNZ;
        float rs = 0.f;
        for (int p = 0; p < nn; ++p) {
            int c = wc[wave][p];
            float dc = 0.f;
#pragma unroll
            for (int c0 = 0; c0 < N_; c0 += 64) dc += A[(size_t)c * N_ + c0 + lane];
#pragma unroll
            for (int o = 32; o > 0; o >>= 1) dc += __shfl_xor(dc, o);
            float dinv_c = (dc == 0.f) ? 0.f : 1.0f / sqrtf(dc);
            float v = wa[wave][p] * dinv_i * dinv_c;
            rs += v;
            if (lane == 0) {
                cols[i * MAXNNZ + p] = c;
                vals[i * MAXNNZ + p] = v;
            }
        }
        if (lane == 0) {
            nnzArr[i] = cnt;
            rowsum[i] = rs;
        }
    } else if (blk < 384) {
        int idx = (blk - 192) * 256 + tid;
        if (idx < 128 * 256) W2b[idx] = f2bf(W2[idx]);
        else W3b[idx - 128 * 256] = f2bf(W3[idx - 128 * 256]);
    } else {
        clampf[tid] = 0;
        clampf[tid + 256] = 0;
        clampf[tid + 512] = 0;
        __syncthreads();
        if (tid < np) clampf[psel[tid]] = 1;
        else if (tid - np < n1) clampf[NV_ + c1[tid - np]] = 1;
        else if (tid - np - n1 < n2) clampf[2 * NV_ + c2[tid - np - n1]] = 1;
    }
}

// ---- fused layers 1+2: agg(F=6) -> 6->256 linear+relu (registers) -> MFMA 256->128 ----
// (round-7 version, no swizzle)

__global__ __launch_bounds__(256) void k_layer12(
    const float* __restrict__ x, const float* __restrict__ inputs,
    const int* __restrict__ cols, const float* __restrict__ vals,
    const int* __restrict__ nnzArr, const int* __restrict__ clampf,
    const float* __restrict__ rowsum, const float* __restrict__ W1,
    const float* __restrict__ b1, const unsigned short* __restrict__ W2b,
    const float* __restrict__ b2, unsigned short* __restrict__ T2) {
    __shared__ float Xs[64][6];
    __shared__ float W1T[6][256];
    __shared__ float b1s[256];

    int tid = threadIdx.x;
    int blk = blockIdx.x;
    int i0 = (blk % 12) * 64;
    int base = (blk / 12) * N_;
    int wave = tid >> 6, lane = tid & 63;
    int lrow = lane & 15, kgrp = lane >> 4;

    for (int t = tid; t < 1536; t += 256) {
        int k = t >> 8, c = t & 255;
        W1T[k][c] = W1[c * 6 + k];
    }
    b1s[tid] = b1[tid];

    for (int t = lane; t < 96; t += 64) {
        int f = t % 6, ro = t / 6;
        int i = i0 + wave * 16 + ro;
        int n = nnzArr[i];
        float s = 0.f;
        for (int k = 0; k < n; ++k) {
            int c = cols[i * MAXNNZ + k];
            float val = (f < 3 && clampf[c]) ? inputs[(size_t)(base + c) * 3 + f]
                                             : x[(size_t)(base + c) * 6 + f];
            s += vals[i * MAXNNZ + k] * val;
        }
        Xs[wave * 16 + ro][f] = s;
    }
    __syncthreads();

    int i = i0 + wave * 16 + lrow;
    size_t g = (size_t)(base + i);
    float rs = rowsum[i];
    float xa[6];
#pragma unroll
    for (int k = 0; k < 6; ++k) xa[k] = Xs[wave * 16 + lrow][k];

    f32x4 acc[8];
#pragma unroll
    for (int j = 0; j < 8; ++j) acc[j] = (f32x4){0.f, 0.f, 0.f, 0.f};

#pragma unroll
    for (int s = 0; s < 8; ++s) {
        int c0 = s * 32 + kgrp * 8;
        float h[8];
        f32x4 bv0 = *(const f32x4*)&b1s[c0];
        f32x4 bv1 = *(const f32x4*)&b1s[c0 + 4];
#pragma unroll
        for (int e = 0; e < 4; ++e) {
            h[e] = rs * bv0[e];
            h[4 + e] = rs * bv1[e];
        }
#pragma unroll
        for (int k = 0; k < 6; ++k) {
            f32x4 w0 = *(const f32x4*)&W1T[k][c0];
            f32x4 w1 = *(const f32x4*)&W1T[k][c0 + 4];
#pragma unroll
            for (int e = 0; e < 4; ++e) {
                h[e] += xa[k] * w0[e];
                h[4 + e] += xa[k] * w1[e];
            }
        }
        us8 o;
#pragma unroll
        for (int e = 0; e < 8; ++e) o[e] = f2bf(fmaxf(h[e], 0.f));
        bf16x8 af = __builtin_bit_cast(bf16x8, o);
#pragma unroll
        for (int j = 0; j < 8; ++j) {
            bf16x8 w = ld_bf8(W2b + (size_t)(j * 16 + lrow) * 256 + c0);
            acc[j] = __builtin_amdgcn_mfma_f32_16x16x32_bf16(w, af, acc[j], 0, 0, 0);
        }
    }

#pragma unroll
    for (int j = 0; j < 8; ++j) {
        f32x4 bv = *(const f32x4*)&b2[j * 16 + kgrp * 4];
        us4 o;
#pragma unroll
        for (int e = 0; e < 4; ++e) o[e] = f2bf(acc[j][e] + bv[e]);
        *(us4*)(T2 + g * 128 + j * 16 + kgrp * 4) = o;
    }
}

// ---- fused layer 3 + W4-dot: relu(agg(T2)) -> MFMA 128->128 -> S = T3row @ W4^T ----
// T3 never materialized; S is fp32 (M,3). (no swizzle)

__global__ __launch_bounds__(256) void k_layer3s(
    const unsigned short* __restrict__ T2, const int* __restrict__ cols,
    const float* __restrict__ vals, const int* __restrict__ nnzArr,
    const unsigned short* __restrict__ W3b, const float* __restrict__ b3,
    const float* __restrict__ W4, float* __restrict__ S) {
    __shared__ float W4s[128 * 3];

    int tid = threadIdx.x;
    int blk = blockIdx.x;
    int i0 = (blk % 12) * 64;
    int base = (blk / 12) * N_;
    int wave = tid >> 6, lane = tid & 63;
    int lrow = lane & 15, kgrp = lane >> 4;

    for (int t = tid; t < 384; t += 256) {
        int d = t % 3, nfeat = t / 3;
        W4s[t] = W4[d * 128 + nfeat];
    }
    __syncthreads();

    int i = i0 + wave * 16 + lrow;
    size_t g = (size_t)(base + i);
    int n = nnzArr[i];
    if (n > MAXNNZ) n = MAXNNZ;

    float fa[4][8];
#pragma unroll
    for (int s = 0; s < 4; ++s)
#pragma unroll
        for (int e = 0; e < 8; ++e) fa[s][e] = 0.f;

    for (int k = 0; k < n; ++k) {
        int c = cols[i * MAXNNZ + k];
        float v = vals[i * MAXNNZ + k];
        const unsigned short* p = T2 + (size_t)(base + c) * 128 + kgrp * 8;
#pragma unroll
        for (int s = 0; s < 4; ++s) {
            us8 z = *(const us8*)(p + s * 32);
#pragma unroll
            for (int e = 0; e < 8; ++e) fa[s][e] += v * bf2f(z[e]);
        }
    }

    bf16x8 af[4];
#pragma unroll
    for (int s = 0; s < 4; ++s) {
        us8 o;
#pragma unroll
        for (int e = 0; e < 8; ++e) o[e] = f2bf(fmaxf(fa[s][e], 0.f));
        af[s] = __builtin_bit_cast(bf16x8, o);
    }

    f32x4 acc[8];
#pragma unroll
    for (int j = 0; j < 8; ++j) acc[j] = (f32x4){0.f, 0.f, 0.f, 0.f};
#pragma unroll
    for (int s = 0; s < 4; ++s) {
#pragma unroll
        for (int j = 0; j < 8; ++j) {
            bf16x8 w = ld_bf8(W3b + (size_t)(j * 16 + lrow) * 128 + s * 32 + kgrp * 8);
            acc[j] = __builtin_amdgcn_mfma_f32_16x16x32_bf16(w, af[s], acc[j], 0, 0, 0);
        }
    }

    // epilogue: fp32 T3 row dotted with W4 -> S[g][0..2]
    float s0 = 0.f, s1 = 0.f, s2 = 0.f;
#pragma unroll
    for (int j = 0; j < 8; ++j) {
        f32x4 bv = *(const f32x4*)&b3[j * 16 + kgrp * 4];
#pragma unroll
        for (int e = 0; e < 4; ++e) {
            float tv = acc[j][e] + bv[e];
            int nfeat = j * 16 + kgrp * 4 + e;
            s0 += tv * W4s[nfeat * 3 + 0];
            s1 += tv * W4s[nfeat * 3 + 1];
            s2 += tv * W4s[nfeat * 3 + 2];
        }
    }
    s0 += __shfl_xor(s0, 16); s0 += __shfl_xor(s0, 32);
    s1 += __shfl_xor(s1, 16); s1 += __shfl_xor(s1, 32);
    s2 += __shfl_xor(s2, 16); s2 += __shfl_xor(s2, 32);
    if (kgrp == 0) {
        S[g * 3 + 0] = s0;
        S[g * 3 + 1] = s1;
        S[g * 3 + 2] = s2;
    }
}

// ---- U = A * S (F=3 agg, no bias/clamp) ----

__global__ __launch_bounds__(256) void k_aggS(const float* __restrict__ S,
                                              const int* __restrict__ cols,
                                              const float* __restrict__ vals,
                                              const int* __restrict__ nnzArr,
                                              float* __restrict__ U) {
    int idx = blockIdx.x * 256 + threadIdx.x;
    if (idx >= M_ * 3) return;
    int f = idx % 3;
    int r = idx / 3;
    int i = r % N_;
    int base = r - i;
    int n = nnzArr[i];
    if (n > MAXNNZ) n = MAXNNZ;
    float s = 0.f;
    for (int k = 0; k < n; ++k) {
        int c = cols[i * MAXNNZ + k];
        s += vals[i * MAXNNZ + k] * S[(size_t)(base + c) * 3 + f];
    }
    U[idx] = s;
}

// ---- final: out = A * U + rowsum*b4, with output clamp ----

__global__ __launch_bounds__(256) void k_out(const float* __restrict__ U,
                                             const float* __restrict__ inputs,
                                             const int* __restrict__ cols,
                                             const float* __restrict__ vals,
                                             const int* __restrict__ nnzArr,
                                             const float* __restrict__ rowsum,
                                             const float* __restrict__ b4,
                                             const int* __restrict__ clampf,
                                             float* __restrict__ out) {
    int idx = blockIdx.x * 256 + threadIdx.x;
    if (idx >= M_ * 3) return;
    int f = idx % 3;
    int r = idx / 3;
    int i = r % N_;
    int base = r - i;
    if (clampf[i]) {
        out[idx] = inputs[(size_t)r * 3 + f];
        return;
    }
    int n = nnzArr[i];
    if (n > MAXNNZ) n = MAXNNZ;
    float s = rowsum[i] * b4[f];
    for (int k = 0; k < n; ++k) {
        int c = cols[i * MAXNNZ + k];
        s += vals[i * MAXNNZ + k] * U[(size_t)(base + c) * 3 + f];
    }
    out[idx] = s;
}

// ---------------- launch ----------------

extern "C" void kernel_launch(void* const* d_in, const int* in_sizes, int n_in,
                              void* d_out, int out_size, void* d_ws, size_t ws_size,
                              hipStream_t stream) {
    const float* x      = (const float*)d_in[0];
    const float* inputs = (const float*)d_in[1];
    const float* A      = (const float*)d_in[2];
    const float* W1     = (const float*)d_in[3];
    const float* b1     = (const float*)d_in[4];
    const float* W2     = (const float*)d_in[5];
    const float* b2     = (const float*)d_in[6];
    const float* W3     = (const float*)d_in[7];
    const float* b3     = (const float*)d_in[8];
    const float* W4     = (const float*)d_in[9];
    const float* b4     = (const float*)d_in[10];
    const int* psel     = (const int*)d_in[11];
    const int* c1sel    = (const int*)d_in[12];
    const int* c2sel    = (const int*)d_in[13];
    int np = in_sizes[11], n1 = in_sizes[12], n2 = in_sizes[13];
    float* out = (float*)d_out;

    char* ws = (char*)d_ws;
    float* rowsum          = (float*)(ws + 3072);
    int*   nnzA            = (int*)(ws + 6144);
    int*   clampf          = (int*)(ws + 9216);
    int*   cols            = (int*)(ws + 12288);
    float* vals            = (float*)(ws + 61440);
    unsigned short* W2b    = (unsigned short*)(ws + 110592);
    unsigned short* W3b    = (unsigned short*)(ws + 176128);
    float* S               = (float*)(ws + 417792);
    float* U               = (float*)(ws + 1048576);
    unsigned short* T2     = (unsigned short*)(ws + 27144192);

    k_prep<<<385, 256, 0, stream>>>(A, W2, W3, psel, np, c1sel, n1, c2sel, n2,
                                    cols, vals, nnzA, rowsum, clampf, W2b, W3b);

    k_layer12<<<M_ / 64, 256, 0, stream>>>(x, inputs, cols, vals, nnzA, clampf, rowsum,
                                           W1, b1, W2b, b2, T2);
    k_layer3s<<<M_ / 64, 256, 0, stream>>>(T2, cols, vals, nnzA, W3b, b3, W4, S);
    k_aggS<<<(M_ * 3 + 255) / 256, 256, 0, stream>>>(S, cols, vals, nnzA, U);
    k_out<<<(M_ * 3 + 255) / 256, 256, 0, stream>>>(U, inputs, cols, vals, nnzA,
                                                    rowsum, b4, clampf, out);
}